// Round 3
// baseline (717.492 us; speedup 1.0000x reference)
//
#include <hip/hip_runtime.h>

#define F_IN  500
#define F_HID 20
#define F_OUT 3

// ---------------- int degree count ----------------
__global__ void k_degree(const int* __restrict__ dst, int* __restrict__ deg, int E) {
    int i = blockIdx.x * blockDim.x + threadIdx.x;
    if (i < E) atomicAdd(&deg[dst[i]], 1);
}

// ---------------- scan stage 1: per-block exclusive scan (1024 elems/block) ----------------
__global__ void k_scan_blk(const int* __restrict__ deg, int* __restrict__ rowstart,
                           int* __restrict__ blocksums, int N) {
    __shared__ int lds[256];
    int tid = threadIdx.x;
    int base = blockIdx.x * 1024 + tid * 4;
    int4 v = make_int4(0, 0, 0, 0);
    if (base + 3 < N) {
        v = *(const int4*)(deg + base);
    } else {
        if (base + 0 < N) v.x = deg[base + 0];
        if (base + 1 < N) v.y = deg[base + 1];
        if (base + 2 < N) v.z = deg[base + 2];
        if (base + 3 < N) v.w = deg[base + 3];
    }
    int tsum = v.x + v.y + v.z + v.w;
    lds[tid] = tsum;
    __syncthreads();
    for (int off = 1; off < 256; off <<= 1) {
        int t = (tid >= off) ? lds[tid - off] : 0;
        __syncthreads();
        lds[tid] += t;
        __syncthreads();
    }
    int excl = lds[tid] - tsum;
    if (tid == 255) blocksums[blockIdx.x] = lds[255];
    int r = excl;
    if (base + 0 < N) rowstart[base + 0] = r; r += v.x;
    if (base + 1 < N) rowstart[base + 1] = r; r += v.y;
    if (base + 2 < N) rowstart[base + 2] = r; r += v.z;
    if (base + 3 < N) rowstart[base + 3] = r;
}

// ---------------- scan stage 2: exclusive scan of block sums (NB <= 256) ----------------
__global__ void k_scan_sums(int* __restrict__ blocksums, int NB) {
    __shared__ int lds[256];
    int tid = threadIdx.x;
    int v = (tid < NB) ? blocksums[tid] : 0;
    lds[tid] = v;
    __syncthreads();
    for (int off = 1; off < 256; off <<= 1) {
        int t = (tid >= off) ? lds[tid - off] : 0;
        __syncthreads();
        lds[tid] += t;
        __syncthreads();
    }
    if (tid < NB) blocksums[tid] = lds[tid] - v;
}

// ---------------- scan stage 3: add block offsets ----------------
__global__ void k_scan_add(int* __restrict__ rowstart, const int* __restrict__ blocksums, int N) {
    int i = blockIdx.x * blockDim.x + threadIdx.x;
    if (i < N) rowstart[i] += blocksums[i >> 10];
}

// ---------------- CSR fill: after this, rowstart[n] == row END ----------------
__global__ void k_fill(const int* __restrict__ src, const int* __restrict__ dst,
                       int* __restrict__ rowstart, int* __restrict__ csr, int E) {
    int e = blockIdx.x * blockDim.x + threadIdx.x;
    if (e >= E) return;
    int pos = atomicAdd(&rowstart[dst[e]], 1);
    csr[pos] = src[e];
}

// ---------------- layer-1 projections: LDS-staged tile GEMM ----------------
// Block = 256 threads = 64 rows. k-tiles of 100 staged transposed in LDS
// (lds[k][row], row-stride 65 -> conflict-free compute reads).
// Thread (r = tid&63, g = tid>>6): g wave-uniform -> W loads are scalar.
__global__ __launch_bounds__(256) void k_gemm1(const float* __restrict__ x,
                        const float* __restrict__ Wl,
                        const float* __restrict__ Wr,
                        float* __restrict__ yl, float* __restrict__ yr, int N) {
    __shared__ float lds[100 * 65];
    const int tid = threadIdx.x;
    const int row0 = blockIdx.x * 64;
    const int r = tid & 63;
    const int g = tid >> 6;                    // 0..3, uniform per wave
    const float* Wg = (g < 2) ? (Wl + g * 10) : (Wr + (g - 2) * 10);

    float acc[10];
#pragma unroll
    for (int c = 0; c < 10; ++c) acc[c] = 0.f;

    for (int t = 0; t < 5; ++t) {
        // stage 64 rows x 100 k (25 float4/row), transposed into LDS
        for (int i = tid; i < 64 * 25; i += 256) {
            int rr = i / 25;
            int cc = i - rr * 25;
            int grow = row0 + rr;
            float4 v = make_float4(0.f, 0.f, 0.f, 0.f);
            if (grow < N)
                v = *(const float4*)(x + (size_t)grow * F_IN + t * 100 + cc * 4);
            int kb = cc * 4;
            lds[(kb + 0) * 65 + rr] = v.x;
            lds[(kb + 1) * 65 + rr] = v.y;
            lds[(kb + 2) * 65 + rr] = v.z;
            lds[(kb + 3) * 65 + rr] = v.w;
        }
        __syncthreads();
        const float* wbase = Wg + (size_t)(t * 100) * F_HID;
#pragma unroll 4
        for (int k = 0; k < 100; ++k) {
            float xv = lds[k * 65 + r];
            const float* w = wbase + k * F_HID;
#pragma unroll
            for (int c = 0; c < 10; ++c) acc[c] += xv * w[c];
        }
        __syncthreads();
    }

    int row = row0 + r;
    if (row < N) {
        float* outp = (g < 2) ? (yl + (size_t)row * F_HID + g * 10)
                              : (yr + (size_t)row * F_HID + (g - 2) * 10);
#pragma unroll
        for (int c = 0; c < 10; ++c) outp[c] = acc[c];
    }
}

// ---------------- gather-aggregate layer 1: thread per (node, 4-col group) ----------------
__global__ void k_agg1(const int* __restrict__ rowend, const int* __restrict__ deg,
                       const int* __restrict__ csr, const float* __restrict__ yl,
                       float* __restrict__ agg1, int N) {
    int i = blockIdx.x * blockDim.x + threadIdx.x;
    if (i >= N * 5) return;
    int n = i / 5;
    int cg = i - n * 5;
    int d = deg[n];
    int beg = rowend[n] - d;
    float4 acc = make_float4(0.f, 0.f, 0.f, 0.f);
    for (int j = 0; j < d; ++j) {
        int s = csr[beg + j];
        float4 v = *(const float4*)(yl + (size_t)s * F_HID + cg * 4);
        acc.x += v.x; acc.y += v.y; acc.z += v.z; acc.w += v.w;
    }
    *(float4*)(agg1 + (size_t)n * F_HID + cg * 4) = acc;
}

// ---------------- layer1 epilogue + layer2 projections ----------------
__global__ void k_layer1(const int* __restrict__ deg,
                         const float* __restrict__ agg1,
                         const float* __restrict__ yr,
                         const float* __restrict__ b1,
                         const float* __restrict__ W2l,
                         const float* __restrict__ W2r,
                         float* __restrict__ zl, float* __restrict__ zr, int N) {
    int n = blockIdx.x * blockDim.x + threadIdx.x;
    if (n >= N) return;
    float di = 1.0f / fmaxf((float)deg[n], 1.0f);
    float h[F_HID];
    const float4* pa = (const float4*)(agg1 + (size_t)n * F_HID);
    const float4* pr = (const float4*)(yr + (size_t)n * F_HID);
#pragma unroll
    for (int q = 0; q < F_HID / 4; ++q) {
        float4 a = pa[q];
        float4 r = pr[q];
        h[4*q+0] = fmaxf(a.x * di + b1[4*q+0] + r.x, 0.f);
        h[4*q+1] = fmaxf(a.y * di + b1[4*q+1] + r.y, 0.f);
        h[4*q+2] = fmaxf(a.z * di + b1[4*q+2] + r.z, 0.f);
        h[4*q+3] = fmaxf(a.w * di + b1[4*q+3] + r.w, 0.f);
    }
    float zlo[F_OUT] = {0.f, 0.f, 0.f};
    float zro[F_OUT] = {0.f, 0.f, 0.f};
#pragma unroll
    for (int c = 0; c < F_HID; ++c) {
#pragma unroll
        for (int o = 0; o < F_OUT; ++o) {
            zlo[o] += h[c] * W2l[c * F_OUT + o];
            zro[o] += h[c] * W2r[c * F_OUT + o];
        }
    }
#pragma unroll
    for (int o = 0; o < F_OUT; ++o) {
        zl[(size_t)n * F_OUT + o] = zlo[o];
        zr[(size_t)n * F_OUT + o] = zro[o];
    }
}

// ---------------- gather-aggregate layer 2 + final combine ----------------
__global__ void k_agg2_final(const int* __restrict__ rowend, const int* __restrict__ deg,
                             const int* __restrict__ csr, const float* __restrict__ zl,
                             const float* __restrict__ zr, const float* __restrict__ b2,
                             float* __restrict__ out, int N) {
    int n = blockIdx.x * blockDim.x + threadIdx.x;
    if (n >= N) return;
    int d = deg[n];
    int beg = rowend[n] - d;
    float a0 = 0.f, a1 = 0.f, a2 = 0.f;
    for (int j = 0; j < d; ++j) {
        int s = csr[beg + j];
        const float* z = zl + (size_t)s * F_OUT;
        a0 += z[0]; a1 += z[1]; a2 += z[2];
    }
    float di = 1.0f / fmaxf((float)d, 1.0f);
    out[(size_t)n * F_OUT + 0] = a0 * di + b2[0] + zr[(size_t)n * F_OUT + 0];
    out[(size_t)n * F_OUT + 1] = a1 * di + b2[1] + zr[(size_t)n * F_OUT + 1];
    out[(size_t)n * F_OUT + 2] = a2 * di + b2[2] + zr[(size_t)n * F_OUT + 2];
}

extern "C" void kernel_launch(void* const* d_in, const int* in_sizes, int n_in,
                              void* d_out, int out_size, void* d_ws, size_t ws_size,
                              hipStream_t stream) {
    const float* x   = (const float*)d_in[0];
    const int*   ei  = (const int*)d_in[1];
    const float* W1l = (const float*)d_in[2];
    const float* W1r = (const float*)d_in[3];
    const float* b1  = (const float*)d_in[4];
    const float* W2l = (const float*)d_in[5];
    const float* W2r = (const float*)d_in[6];
    const float* b2  = (const float*)d_in[7];
    float* out = (float*)d_out;

    const int N = in_sizes[0] / F_IN;     // 100000
    const int E = in_sizes[1] / 2;        // 800000
    const int* src = ei;
    const int* dst = ei + E;

    // workspace layout
    int*   wsi      = (int*)d_ws;
    int*   deg      = wsi;                        // N (memset to 0)
    int*   rowstart = deg + N;                    // N
    int*   blocksums= rowstart + N;               // 256
    int*   csr      = blocksums + 256;            // E
    float* yl       = (float*)(csr + E);          // N*20
    float* yr       = yl + (size_t)N * F_HID;     // N*20
    float* agg1     = yr + (size_t)N * F_HID;     // N*20
    float* zl       = agg1 + (size_t)N * F_HID;   // N*3
    float* zr       = zl + (size_t)N * F_OUT;     // N*3

    hipMemsetAsync(deg, 0, (size_t)N * sizeof(int), stream);

    const int B = 256;
    const int NB = (N + 1023) / 1024;   // 98 <= 256
    k_degree    <<<(E + B - 1) / B, B, 0, stream>>>(dst, deg, E);
    k_scan_blk  <<<NB, 256, 0, stream>>>(deg, rowstart, blocksums, N);
    k_scan_sums <<<1, 256, 0, stream>>>(blocksums, NB);
    k_scan_add  <<<(N + B - 1) / B, B, 0, stream>>>(rowstart, blocksums, N);
    k_fill      <<<(E + B - 1) / B, B, 0, stream>>>(src, dst, rowstart, csr, E);
    k_gemm1     <<<(N + 63) / 64, 256, 0, stream>>>(x, W1l, W1r, yl, yr, N);
    k_agg1      <<<(N * 5 + B - 1) / B, B, 0, stream>>>(rowstart, deg, csr, yl, agg1, N);
    k_layer1    <<<(N + B - 1) / B, B, 0, stream>>>(deg, agg1, yr, b1, W2l, W2r, zl, zr, N);
    k_agg2_final<<<(N + B - 1) / B, B, 0, stream>>>(rowstart, deg, csr, zl, zr, b2, out, N);
}

// Round 4
// 549.854 us; speedup vs baseline: 1.3049x; 1.3049x over previous
//
#include <hip/hip_runtime.h>

#define F_IN  500
#define F_HID 20
#define F_OUT 3

// ---------------- int degree count ----------------
__global__ void k_degree(const int* __restrict__ dst, int* __restrict__ deg, int E) {
    int i = blockIdx.x * blockDim.x + threadIdx.x;
    if (i < E) atomicAdd(&deg[dst[i]], 1);
}

// ---------------- scan stage 1: per-block exclusive scan (1024 elems/block) ----------------
__global__ void k_scan_blk(const int* __restrict__ deg, int* __restrict__ rowstart,
                           int* __restrict__ blocksums, int N) {
    __shared__ int lds[256];
    int tid = threadIdx.x;
    int base = blockIdx.x * 1024 + tid * 4;
    int4 v = make_int4(0, 0, 0, 0);
    if (base + 3 < N) {
        v = *(const int4*)(deg + base);
    } else {
        if (base + 0 < N) v.x = deg[base + 0];
        if (base + 1 < N) v.y = deg[base + 1];
        if (base + 2 < N) v.z = deg[base + 2];
        if (base + 3 < N) v.w = deg[base + 3];
    }
    int tsum = v.x + v.y + v.z + v.w;
    lds[tid] = tsum;
    __syncthreads();
    for (int off = 1; off < 256; off <<= 1) {
        int t = (tid >= off) ? lds[tid - off] : 0;
        __syncthreads();
        lds[tid] += t;
        __syncthreads();
    }
    int excl = lds[tid] - tsum;
    if (tid == 255) blocksums[blockIdx.x] = lds[255];
    int r = excl;
    if (base + 0 < N) rowstart[base + 0] = r; r += v.x;
    if (base + 1 < N) rowstart[base + 1] = r; r += v.y;
    if (base + 2 < N) rowstart[base + 2] = r; r += v.z;
    if (base + 3 < N) rowstart[base + 3] = r;
}

// ---------------- scan stage 2: exclusive scan of block sums (NB <= 256) ----------------
__global__ void k_scan_sums(int* __restrict__ blocksums, int NB) {
    __shared__ int lds[256];
    int tid = threadIdx.x;
    int v = (tid < NB) ? blocksums[tid] : 0;
    lds[tid] = v;
    __syncthreads();
    for (int off = 1; off < 256; off <<= 1) {
        int t = (tid >= off) ? lds[tid - off] : 0;
        __syncthreads();
        lds[tid] += t;
        __syncthreads();
    }
    if (tid < NB) blocksums[tid] = lds[tid] - v;
}

// ---------------- scan stage 3: add block offsets ----------------
__global__ void k_scan_add(int* __restrict__ rowstart, const int* __restrict__ blocksums, int N) {
    int i = blockIdx.x * blockDim.x + threadIdx.x;
    if (i < N) rowstart[i] += blocksums[i >> 10];
}

// ---------------- CSR fill: after this, rowstart[n] == row END ----------------
__global__ void k_fill(const int* __restrict__ src, const int* __restrict__ dst,
                       int* __restrict__ rowstart, int* __restrict__ csr, int E) {
    int e = blockIdx.x * blockDim.x + threadIdx.x;
    if (e >= E) return;
    int pos = atomicAdd(&rowstart[dst[e]], 1);
    csr[pos] = src[e];
}

// ---------------- layer-1 projections, k-split x5 ----------------
// Block = 320 threads = 64 rows x 5 k-slices (100 k each, float4-aligned).
// ks forced to SGPR via readfirstlane -> W loads stay scalar (the R3 bug).
// Partials merged via LDS atomicAdd into 64x41 (pad -> conflict-free).
// Output y[row][40] interleaved: cols 0..19 = x@W1l, 20..39 = x@W1r.
__global__ __launch_bounds__(320) void k_gemm1(const float* __restrict__ x,
                        const float* __restrict__ Wl,
                        const float* __restrict__ Wr,
                        float* __restrict__ y, int N) {
    __shared__ float sacc[64 * 41];
    const int tid = threadIdx.x;
    for (int i = tid; i < 64 * 41; i += 320) sacc[i] = 0.f;
    __syncthreads();

    const int r = tid & 63;
    const int ks = __builtin_amdgcn_readfirstlane(tid >> 6);  // 0..4, wave-uniform
    const int row = blockIdx.x * 64 + r;

    float acc[40];
#pragma unroll
    for (int c = 0; c < 40; ++c) acc[c] = 0.f;

    if (row < N) {
        const float4* xp = (const float4*)(x + (size_t)row * F_IN + ks * 100);
        const float* wl = Wl + (size_t)ks * 100 * F_HID;
        const float* wr = Wr + (size_t)ks * 100 * F_HID;
#pragma unroll 5
        for (int k4 = 0; k4 < 25; ++k4) {
            float4 v = xp[k4];
            float xs[4] = {v.x, v.y, v.z, v.w};
#pragma unroll
            for (int j = 0; j < 4; ++j) {
                int k = k4 * 4 + j;
#pragma unroll
                for (int c = 0; c < F_HID; ++c) {
                    acc[c]          += xs[j] * wl[k * F_HID + c];
                    acc[F_HID + c]  += xs[j] * wr[k * F_HID + c];
                }
            }
        }
#pragma unroll
        for (int c = 0; c < 40; ++c) atomicAdd(&sacc[r * 41 + c], acc[c]);
    }
    __syncthreads();

    const int row0 = blockIdx.x * 64;
    for (int o = tid; o < 64 * 40; o += 320) {
        int rr = o / 40;
        int c  = o - rr * 40;
        int grow = row0 + rr;
        if (grow < N) y[(size_t)grow * 40 + c] = sacc[rr * 41 + c];
    }
}

// ---------------- gather-aggregate layer 1: thread per (node, 4-col group) ----------------
// yl lives in y[row][0..20)
__global__ void k_agg1(const int* __restrict__ rowend, const int* __restrict__ deg,
                       const int* __restrict__ csr, const float* __restrict__ y,
                       float* __restrict__ agg1, int N) {
    int i = blockIdx.x * blockDim.x + threadIdx.x;
    if (i >= N * 5) return;
    int n = i / 5;
    int cg = i - n * 5;
    int d = deg[n];
    int beg = rowend[n] - d;
    float4 acc = make_float4(0.f, 0.f, 0.f, 0.f);
    for (int j = 0; j < d; ++j) {
        int s = csr[beg + j];
        float4 v = *(const float4*)(y + (size_t)s * 40 + cg * 4);
        acc.x += v.x; acc.y += v.y; acc.z += v.z; acc.w += v.w;
    }
    *(float4*)(agg1 + (size_t)n * F_HID + cg * 4) = acc;
}

// ---------------- layer1 epilogue + layer2 projections ----------------
// yr lives in y[row][20..40)
__global__ void k_layer1(const int* __restrict__ deg,
                         const float* __restrict__ agg1,
                         const float* __restrict__ y,
                         const float* __restrict__ b1,
                         const float* __restrict__ W2l,
                         const float* __restrict__ W2r,
                         float* __restrict__ zl, float* __restrict__ zr, int N) {
    int n = blockIdx.x * blockDim.x + threadIdx.x;
    if (n >= N) return;
    float di = 1.0f / fmaxf((float)deg[n], 1.0f);
    float h[F_HID];
    const float4* pa = (const float4*)(agg1 + (size_t)n * F_HID);
    const float4* pr = (const float4*)(y + (size_t)n * 40 + F_HID);
#pragma unroll
    for (int q = 0; q < F_HID / 4; ++q) {
        float4 a = pa[q];
        float4 r = pr[q];
        h[4*q+0] = fmaxf(a.x * di + b1[4*q+0] + r.x, 0.f);
        h[4*q+1] = fmaxf(a.y * di + b1[4*q+1] + r.y, 0.f);
        h[4*q+2] = fmaxf(a.z * di + b1[4*q+2] + r.z, 0.f);
        h[4*q+3] = fmaxf(a.w * di + b1[4*q+3] + r.w, 0.f);
    }
    float zlo[F_OUT] = {0.f, 0.f, 0.f};
    float zro[F_OUT] = {0.f, 0.f, 0.f};
#pragma unroll
    for (int c = 0; c < F_HID; ++c) {
#pragma unroll
        for (int o = 0; o < F_OUT; ++o) {
            zlo[o] += h[c] * W2l[c * F_OUT + o];
            zro[o] += h[c] * W2r[c * F_OUT + o];
        }
    }
#pragma unroll
    for (int o = 0; o < F_OUT; ++o) {
        zl[(size_t)n * F_OUT + o] = zlo[o];
        zr[(size_t)n * F_OUT + o] = zro[o];
    }
}

// ---------------- gather-aggregate layer 2 + final combine ----------------
__global__ void k_agg2_final(const int* __restrict__ rowend, const int* __restrict__ deg,
                             const int* __restrict__ csr, const float* __restrict__ zl,
                             const float* __restrict__ zr, const float* __restrict__ b2,
                             float* __restrict__ out, int N) {
    int n = blockIdx.x * blockDim.x + threadIdx.x;
    if (n >= N) return;
    int d = deg[n];
    int beg = rowend[n] - d;
    float a0 = 0.f, a1 = 0.f, a2 = 0.f;
    for (int j = 0; j < d; ++j) {
        int s = csr[beg + j];
        const float* z = zl + (size_t)s * F_OUT;
        a0 += z[0]; a1 += z[1]; a2 += z[2];
    }
    float di = 1.0f / fmaxf((float)d, 1.0f);
    out[(size_t)n * F_OUT + 0] = a0 * di + b2[0] + zr[(size_t)n * F_OUT + 0];
    out[(size_t)n * F_OUT + 1] = a1 * di + b2[1] + zr[(size_t)n * F_OUT + 1];
    out[(size_t)n * F_OUT + 2] = a2 * di + b2[2] + zr[(size_t)n * F_OUT + 2];
}

extern "C" void kernel_launch(void* const* d_in, const int* in_sizes, int n_in,
                              void* d_out, int out_size, void* d_ws, size_t ws_size,
                              hipStream_t stream) {
    const float* x   = (const float*)d_in[0];
    const int*   ei  = (const int*)d_in[1];
    const float* W1l = (const float*)d_in[2];
    const float* W1r = (const float*)d_in[3];
    const float* b1  = (const float*)d_in[4];
    const float* W2l = (const float*)d_in[5];
    const float* W2r = (const float*)d_in[6];
    const float* b2  = (const float*)d_in[7];
    float* out = (float*)d_out;

    const int N = in_sizes[0] / F_IN;     // 100000
    const int E = in_sizes[1] / 2;        // 800000
    const int* src = ei;
    const int* dst = ei + E;

    // workspace layout
    int*   wsi      = (int*)d_ws;
    int*   deg      = wsi;                        // N (memset to 0)
    int*   rowstart = deg + N;                    // N
    int*   blocksums= rowstart + N;               // 256
    int*   csr      = blocksums + 256;            // E
    float* y        = (float*)(csr + E);          // N*40 (yl | yr interleaved)
    float* agg1     = y + (size_t)N * 40;         // N*20
    float* zl       = agg1 + (size_t)N * F_HID;   // N*3
    float* zr       = zl + (size_t)N * F_OUT;     // N*3

    hipMemsetAsync(deg, 0, (size_t)N * sizeof(int), stream);

    const int B = 256;
    const int NB = (N + 1023) / 1024;   // 98 <= 256
    k_degree    <<<(E + B - 1) / B, B, 0, stream>>>(dst, deg, E);
    k_scan_blk  <<<NB, 256, 0, stream>>>(deg, rowstart, blocksums, N);
    k_scan_sums <<<1, 256, 0, stream>>>(blocksums, NB);
    k_scan_add  <<<(N + B - 1) / B, B, 0, stream>>>(rowstart, blocksums, N);
    k_fill      <<<(E + B - 1) / B, B, 0, stream>>>(src, dst, rowstart, csr, E);
    k_gemm1     <<<(N + 63) / 64, 320, 0, stream>>>(x, W1l, W1r, y, N);
    k_agg1      <<<(N * 5 + B - 1) / B, B, 0, stream>>>(rowstart, deg, csr, y, agg1, N);
    k_layer1    <<<(N + B - 1) / B, B, 0, stream>>>(deg, agg1, y, b1, W2l, W2r, zl, zr, N);
    k_agg2_final<<<(N + B - 1) / B, B, 0, stream>>>(rowstart, deg, csr, zl, zr, b2, out, N);
}

// Round 5
// 435.207 us; speedup vs baseline: 1.6486x; 1.2634x over previous
//
#include <hip/hip_runtime.h>

#define F_IN  500
#define F_HID 20
#define F_OUT 3
#define KT    16   // k-tiles of 32 (K padded 500 -> 512)
#define NT    3    // n-tiles of 16 (N padded 40 -> 48)

typedef __attribute__((ext_vector_type(8))) short short8;
typedef __attribute__((ext_vector_type(4))) float v4f;

__device__ __forceinline__ unsigned f2bf(float f) {
    unsigned u = __float_as_uint(f);
    u = u + 0x7fffu + ((u >> 16) & 1u);   // round-to-nearest-even
    return u >> 16;
}
__device__ __forceinline__ float bf2f(unsigned h) {
    return __uint_as_float(h << 16);
}

// ---------------- int degree count ----------------
__global__ void k_degree(const int* __restrict__ dst, int* __restrict__ deg, int E) {
    int i = blockIdx.x * blockDim.x + threadIdx.x;
    if (i < E) atomicAdd(&deg[dst[i]], 1);
}

// ---------------- scan stage 1 ----------------
__global__ void k_scan_blk(const int* __restrict__ deg, int* __restrict__ rowstart,
                           int* __restrict__ blocksums, int N) {
    __shared__ int lds[256];
    int tid = threadIdx.x;
    int base = blockIdx.x * 1024 + tid * 4;
    int4 v = make_int4(0, 0, 0, 0);
    if (base + 3 < N) {
        v = *(const int4*)(deg + base);
    } else {
        if (base + 0 < N) v.x = deg[base + 0];
        if (base + 1 < N) v.y = deg[base + 1];
        if (base + 2 < N) v.z = deg[base + 2];
        if (base + 3 < N) v.w = deg[base + 3];
    }
    int tsum = v.x + v.y + v.z + v.w;
    lds[tid] = tsum;
    __syncthreads();
    for (int off = 1; off < 256; off <<= 1) {
        int t = (tid >= off) ? lds[tid - off] : 0;
        __syncthreads();
        lds[tid] += t;
        __syncthreads();
    }
    int excl = lds[tid] - tsum;
    if (tid == 255) blocksums[blockIdx.x] = lds[255];
    int r = excl;
    if (base + 0 < N) rowstart[base + 0] = r; r += v.x;
    if (base + 1 < N) rowstart[base + 1] = r; r += v.y;
    if (base + 2 < N) rowstart[base + 2] = r; r += v.z;
    if (base + 3 < N) rowstart[base + 3] = r;
}

// ---------------- scan stage 2 ----------------
__global__ void k_scan_sums(int* __restrict__ blocksums, int NB) {
    __shared__ int lds[256];
    int tid = threadIdx.x;
    int v = (tid < NB) ? blocksums[tid] : 0;
    lds[tid] = v;
    __syncthreads();
    for (int off = 1; off < 256; off <<= 1) {
        int t = (tid >= off) ? lds[tid - off] : 0;
        __syncthreads();
        lds[tid] += t;
        __syncthreads();
    }
    if (tid < NB) blocksums[tid] = lds[tid] - v;
}

// ---------------- scan stage 3 ----------------
__global__ void k_scan_add(int* __restrict__ rowstart, const int* __restrict__ blocksums, int N) {
    int i = blockIdx.x * blockDim.x + threadIdx.x;
    if (i < N) rowstart[i] += blocksums[i >> 10];
}

// ---------------- CSR fill: after this, rowstart[n] == row END ----------------
__global__ void k_fill(const int* __restrict__ src, const int* __restrict__ dst,
                       int* __restrict__ rowstart, int* __restrict__ csr, int E) {
    int e = blockIdx.x * blockDim.x + threadIdx.x;
    if (e >= E) return;
    int pos = atomicAdd(&rowstart[dst[e]], 1);
    csr[pos] = src[e];
}

// ---------------- pack W into B-fragment-order bf16 hi/lo ----------------
// B-frag (16x16x32): lane holds B[k = kt*32 + (lane>>4)*8 + j][n = nt*16 + (lane&15)],
// j=0..7 contiguous. cols 0..19 = W1l, 20..39 = W1r, 40..47 = 0.
__global__ void k_prepB(const float* __restrict__ Wl, const float* __restrict__ Wr,
                        unsigned short* __restrict__ Bhi, unsigned short* __restrict__ Blo) {
    int i = blockIdx.x * blockDim.x + threadIdx.x;   // (kt*NT+nt)*64 + lane
    if (i >= KT * NT * 64) return;
    int lane = i & 63;
    int ntk  = i >> 6;
    int nt   = ntk % NT;
    int kt   = ntk / NT;
    int n     = nt * 16 + (lane & 15);
    int kbase = kt * 32 + (lane >> 4) * 8;
#pragma unroll
    for (int j = 0; j < 8; ++j) {
        int k = kbase + j;
        float w = 0.f;
        if (k < F_IN && n < 2 * F_HID)
            w = (n < F_HID) ? Wl[k * F_HID + n] : Wr[k * F_HID + (n - F_HID)];
        unsigned h = f2bf(w);
        Bhi[(size_t)i * 8 + j] = (unsigned short)h;
        Blo[(size_t)i * 8 + j] = (unsigned short)f2bf(w - bf2f(h));
    }
}

// ---------------- layer-1 projections via MFMA (split-bf16, 3-term) ----------------
// Block = 256 thr = 4 waves; wave w owns rows row0 + w*16 .. +15.
// Per 32-k chunk: stage x (fp32 -> bf16 hi/lo) in LDS, A-frags via ds_read_b128,
// B-frags direct from global (L1/L2-hot), 9 MFMAs (3 ntiles x 3 split terms).
__global__ __launch_bounds__(256) void k_gemm1(const float* __restrict__ x,
        const unsigned short* __restrict__ Bhi, const unsigned short* __restrict__ Blo,
        float* __restrict__ y, int N) {
    __shared__ unsigned short xhi[64 * 32];
    __shared__ unsigned short xlo[64 * 32];
    const int tid  = threadIdx.x;
    const int lane = tid & 63;
    const int wv   = tid >> 6;
    const int row0 = blockIdx.x * 64;

    v4f acc[NT];
#pragma unroll
    for (int nt = 0; nt < NT; ++nt) { acc[nt][0]=0.f; acc[nt][1]=0.f; acc[nt][2]=0.f; acc[nt][3]=0.f; }

    const int srow = tid >> 3;        // 0..31 (plus +32 second half)
    const int skc  = (tid & 7) * 4;   // float4 offset in 32-k chunk
    const int arow = wv * 16 + (lane & 15);
    const int ak   = (lane >> 4) * 8;

    for (int kt = 0; kt < KT; ++kt) {
        // ---- stage 64 rows x 32 k ----
#pragma unroll
        for (int hh = 0; hh < 2; ++hh) {
            int rl   = srow + hh * 32;
            int grow = row0 + rl;
            int gk   = kt * 32 + skc;
            float4 v = make_float4(0.f, 0.f, 0.f, 0.f);
            if (grow < N && gk + 3 < F_IN)
                v = *(const float4*)(x + (size_t)grow * F_IN + gk);
            unsigned h0 = f2bf(v.x), h1 = f2bf(v.y), h2 = f2bf(v.z), h3 = f2bf(v.w);
            unsigned l0 = f2bf(v.x - bf2f(h0));
            unsigned l1 = f2bf(v.y - bf2f(h1));
            unsigned l2 = f2bf(v.z - bf2f(h2));
            unsigned l3 = f2bf(v.w - bf2f(h3));
            *(uint2*)&xhi[rl * 32 + skc] = make_uint2(h0 | (h1 << 16), h2 | (h3 << 16));
            *(uint2*)&xlo[rl * 32 + skc] = make_uint2(l0 | (l1 << 16), l2 | (l3 << 16));
        }
        __syncthreads();
        // ---- fragments + MFMA ----
        short8 Ah = *(const short8*)&xhi[arow * 32 + ak];
        short8 Al = *(const short8*)&xlo[arow * 32 + ak];
#pragma unroll
        for (int nt = 0; nt < NT; ++nt) {
            size_t fo = (((size_t)kt * NT + nt) * 64 + lane) * 8;
            short8 Bh = *(const short8*)(Bhi + fo);
            short8 Bl = *(const short8*)(Blo + fo);
            acc[nt] = __builtin_amdgcn_mfma_f32_16x16x32_bf16(Ah, Bh, acc[nt], 0, 0, 0);
            acc[nt] = __builtin_amdgcn_mfma_f32_16x16x32_bf16(Ah, Bl, acc[nt], 0, 0, 0);
            acc[nt] = __builtin_amdgcn_mfma_f32_16x16x32_bf16(Al, Bh, acc[nt], 0, 0, 0);
        }
        __syncthreads();
    }
    // ---- epilogue: C/D layout col = lane&15, row = (lane>>4)*4 + reg ----
    int rloc = wv * 16 + (lane >> 4) * 4;
#pragma unroll
    for (int nt = 0; nt < NT; ++nt) {
        int col = nt * 16 + (lane & 15);
        if (col < 2 * F_HID) {
#pragma unroll
            for (int rg = 0; rg < 4; ++rg) {
                int grow = row0 + rloc + rg;
                if (grow < N) y[(size_t)grow * 40 + col] = acc[nt][rg];
            }
        }
    }
}

// ---------------- gather-aggregate layer 1 (yl = y[:,0..20)) ----------------
__global__ void k_agg1(const int* __restrict__ rowend, const int* __restrict__ deg,
                       const int* __restrict__ csr, const float* __restrict__ y,
                       float* __restrict__ agg1, int N) {
    int i = blockIdx.x * blockDim.x + threadIdx.x;
    if (i >= N * 5) return;
    int n = i / 5;
    int cg = i - n * 5;
    int d = deg[n];
    int beg = rowend[n] - d;
    float4 acc = make_float4(0.f, 0.f, 0.f, 0.f);
    for (int j = 0; j < d; ++j) {
        int s = csr[beg + j];
        float4 v = *(const float4*)(y + (size_t)s * 40 + cg * 4);
        acc.x += v.x; acc.y += v.y; acc.z += v.z; acc.w += v.w;
    }
    *(float4*)(agg1 + (size_t)n * F_HID + cg * 4) = acc;
}

// ---------------- layer1 epilogue + layer2 projections (yr = y[:,20..40)) ----------------
__global__ void k_layer1(const int* __restrict__ deg,
                         const float* __restrict__ agg1,
                         const float* __restrict__ y,
                         const float* __restrict__ b1,
                         const float* __restrict__ W2l,
                         const float* __restrict__ W2r,
                         float* __restrict__ zl, float* __restrict__ zr, int N) {
    int n = blockIdx.x * blockDim.x + threadIdx.x;
    if (n >= N) return;
    float di = 1.0f / fmaxf((float)deg[n], 1.0f);
    float h[F_HID];
    const float4* pa = (const float4*)(agg1 + (size_t)n * F_HID);
    const float4* pr = (const float4*)(y + (size_t)n * 40 + F_HID);
#pragma unroll
    for (int q = 0; q < F_HID / 4; ++q) {
        float4 a = pa[q];
        float4 r = pr[q];
        h[4*q+0] = fmaxf(a.x * di + b1[4*q+0] + r.x, 0.f);
        h[4*q+1] = fmaxf(a.y * di + b1[4*q+1] + r.y, 0.f);
        h[4*q+2] = fmaxf(a.z * di + b1[4*q+2] + r.z, 0.f);
        h[4*q+3] = fmaxf(a.w * di + b1[4*q+3] + r.w, 0.f);
    }
    float zlo[F_OUT] = {0.f, 0.f, 0.f};
    float zro[F_OUT] = {0.f, 0.f, 0.f};
#pragma unroll
    for (int c = 0; c < F_HID; ++c) {
#pragma unroll
        for (int o = 0; o < F_OUT; ++o) {
            zlo[o] += h[c] * W2l[c * F_OUT + o];
            zro[o] += h[c] * W2r[c * F_OUT + o];
        }
    }
#pragma unroll
    for (int o = 0; o < F_OUT; ++o) {
        zl[(size_t)n * F_OUT + o] = zlo[o];
        zr[(size_t)n * F_OUT + o] = zro[o];
    }
}

// ---------------- gather-aggregate layer 2 + final combine ----------------
__global__ void k_agg2_final(const int* __restrict__ rowend, const int* __restrict__ deg,
                             const int* __restrict__ csr, const float* __restrict__ zl,
                             const float* __restrict__ zr, const float* __restrict__ b2,
                             float* __restrict__ out, int N) {
    int n = blockIdx.x * blockDim.x + threadIdx.x;
    if (n >= N) return;
    int d = deg[n];
    int beg = rowend[n] - d;
    float a0 = 0.f, a1 = 0.f, a2 = 0.f;
    for (int j = 0; j < d; ++j) {
        int s = csr[beg + j];
        const float* z = zl + (size_t)s * F_OUT;
        a0 += z[0]; a1 += z[1]; a2 += z[2];
    }
    float di = 1.0f / fmaxf((float)d, 1.0f);
    out[(size_t)n * F_OUT + 0] = a0 * di + b2[0] + zr[(size_t)n * F_OUT + 0];
    out[(size_t)n * F_OUT + 1] = a1 * di + b2[1] + zr[(size_t)n * F_OUT + 1];
    out[(size_t)n * F_OUT + 2] = a2 * di + b2[2] + zr[(size_t)n * F_OUT + 2];
}

extern "C" void kernel_launch(void* const* d_in, const int* in_sizes, int n_in,
                              void* d_out, int out_size, void* d_ws, size_t ws_size,
                              hipStream_t stream) {
    const float* x   = (const float*)d_in[0];
    const int*   ei  = (const int*)d_in[1];
    const float* W1l = (const float*)d_in[2];
    const float* W1r = (const float*)d_in[3];
    const float* b1  = (const float*)d_in[4];
    const float* W2l = (const float*)d_in[5];
    const float* W2r = (const float*)d_in[6];
    const float* b2  = (const float*)d_in[7];
    float* out = (float*)d_out;

    const int N = in_sizes[0] / F_IN;     // 100000
    const int E = in_sizes[1] / 2;        // 800000
    const int* src = ei;
    const int* dst = ei + E;

    // workspace layout
    int*   wsi      = (int*)d_ws;
    int*   deg      = wsi;                        // N (memset to 0)
    int*   rowstart = deg + N;                    // N
    int*   blocksums= rowstart + N;               // 256
    int*   csr      = blocksums + 256;            // E
    float* y        = (float*)(csr + E);          // N*40 (yl | yr)
    float* agg1     = y + (size_t)N * 40;         // N*20
    float* zl       = agg1 + (size_t)N * F_HID;   // N*3
    float* zr       = zl + (size_t)N * F_OUT;     // N*3
    unsigned short* Bhi = (unsigned short*)(zr + (size_t)N * F_OUT); // KT*NT*64*8
    unsigned short* Blo = Bhi + (size_t)KT * NT * 64 * 8;

    hipMemsetAsync(deg, 0, (size_t)N * sizeof(int), stream);

    const int B = 256;
    const int NB = (N + 1023) / 1024;   // 98 <= 256
    k_prepB     <<<(KT * NT * 64 + B - 1) / B, B, 0, stream>>>(W1l, W1r, Bhi, Blo);
    k_degree    <<<(E + B - 1) / B, B, 0, stream>>>(dst, deg, E);
    k_scan_blk  <<<NB, 256, 0, stream>>>(deg, rowstart, blocksums, N);
    k_scan_sums <<<1, 256, 0, stream>>>(blocksums, NB);
    k_scan_add  <<<(N + B - 1) / B, B, 0, stream>>>(rowstart, blocksums, N);
    k_fill      <<<(E + B - 1) / B, B, 0, stream>>>(src, dst, rowstart, csr, E);
    k_gemm1     <<<(N + 63) / 64, 256, 0, stream>>>(x, Bhi, Blo, y, N);
    k_agg1      <<<(N * 5 + B - 1) / B, B, 0, stream>>>(rowstart, deg, csr, y, agg1, N);
    k_layer1    <<<(N + B - 1) / B, B, 0, stream>>>(deg, agg1, y, b1, W2l, W2r, zl, zr, N);
    k_agg2_final<<<(N + B - 1) / B, B, 0, stream>>>(rowstart, deg, csr, zl, zr, b2, out, N);
}